// Round 2
// baseline (154.502 us; speedup 1.0000x reference)
//
#include <hip/hip_runtime.h>
#include <stdint.h>

#define B_   8
#define KB_  16
#define SEQ_ 512
#define HID_ 768

#define NKB  (HID_ / 32)         // 24 k-blocks (32 halves each) per row
#define QRB  (B_  * SEQ_ / 16)   // 256 Q row-blocks of 16 rows
#define KRB  (KB_ * SEQ_ / 16)   // 512 K row-blocks

typedef __attribute__((ext_vector_type(4))) _Float16 half4;
typedef __attribute__((ext_vector_type(8))) _Float16 half8;
typedef __attribute__((ext_vector_type(4))) float    floatx4;

#define GLOBAL_AS __attribute__((address_space(1)))
#define LDS_AS    __attribute__((address_space(3)))

// async 16B/lane global->LDS copy: LDS dest = wave-uniform base (+ lane*16 by HW)
static __device__ __forceinline__ void async_tile16(const _Float16* g, _Float16* l)
{
    __builtin_amdgcn_global_load_lds((const GLOBAL_AS uint32_t*)g,
                                     (LDS_AS uint32_t*)l, 16, 0, 0);
}

// ---------------- prepass: L2-normalize rows -> fp16 in MFMA-fragment-tiled layout ----
// Tile = 16 rows x 32 k = 1KB, lane-major: element(row,k) at lane = row | ((k>>3)<<4),
// idx = k&7. One 256-thread block per 16-row block.
#define LP 776   // LDS row stride in halves

__global__ __launch_bounds__(256)
void prep_tile(const float* __restrict__ Q, const float* __restrict__ K,
               _Float16* __restrict__ Qt, _Float16* __restrict__ Kt)
{
    const int rb = blockIdx.x;   // 0..767
    const float* src;
    _Float16*    dst;
    if (rb < QRB) { src = Q + (size_t)rb * 16 * HID_;          dst = Qt + (size_t)rb * NKB * 512; }
    else          { src = K + (size_t)(rb - QRB) * 16 * HID_;  dst = Kt + (size_t)(rb - QRB) * NKB * 512; }

    __shared__ _Float16 Ls[16 * LP];
    const int wave = threadIdx.x >> 6;
    const int lane = threadIdx.x & 63;

#pragma unroll
    for (int rr = 0; rr < 4; ++rr) {
        int row = wave * 4 + rr;
        const float* s = src + (size_t)row * HID_;
        float4 v[3];
        float ss = 0.f;
#pragma unroll
        for (int it = 0; it < 3; ++it) {
            v[it] = *(const float4*)(s + lane * 4 + it * 256);
            ss += v[it].x * v[it].x + v[it].y * v[it].y + v[it].z * v[it].z + v[it].w * v[it].w;
        }
#pragma unroll
        for (int m = 1; m < 64; m <<= 1) ss += __shfl_xor(ss, m, 64);
        float sc = 1.0f / fmaxf(sqrtf(ss), 1e-12f);
#pragma unroll
        for (int it = 0; it < 3; ++it) {
            half4 h = { (_Float16)(v[it].x * sc), (_Float16)(v[it].y * sc),
                        (_Float16)(v[it].z * sc), (_Float16)(v[it].w * sc) };
            *(half4*)(Ls + row * LP + lane * 4 + it * 256) = h;
        }
    }
    __syncthreads();

#pragma unroll
    for (int rep = 0; rep < 6; ++rep) {
        int slot = rep * 256 + threadIdx.x;      // 0..1535 = 24 tiles x 64 lanes
        int kb   = slot >> 6;
        int ln   = slot & 63;
        int row  = ln & 15;
        int ko   = kb * 32 + (ln >> 4) * 8;
        half8 h = *(const half8*)(Ls + row * LP + ko);
        *(half8*)(dst + (size_t)kb * 512 + (size_t)ln * 8) = h;
    }
}

// ---------------- phase 1: 256x256 tile GEMM, 2-phase/K-tile interleave ---------------
// grid: x = st2*2 + tb (4), y = j (16), z = i (8); 512 threads = 8 waves (2 row-halves
// x 4 col-quarters), per-wave output 128x64, acc[8][4].
// 3 LDS buffers (32KB each), prefetch distance 2 K-tiles. Per K-tile: 2 phases, each
// {ds_read subtile + stage-issue -> barrier -> lgkmcnt(0) -> 16 MFMA -> barrier}.
// One counted vmcnt(4) per K-tile boundary (tail drains with vmcnt(0)).
__global__ __launch_bounds__(512, 2)
void li_part(const _Float16* __restrict__ Qt, const _Float16* __restrict__ Kt,
             const float* __restrict__ alpha_p, const int* __restrict__ kmask,
             float* __restrict__ Pbuf)
{
    const int st2 = blockIdx.x >> 1;  // s tile (0..1), 256 rows
    const int tb  = blockIdx.x & 1;   // t half (0..1), 256 cols
    const int j   = blockIdx.y;
    const int i   = blockIdx.z;

    const int tid  = threadIdx.x;
    const int lane = tid & 63;
    const int wave = tid >> 6;        // 0..7
    const int quad = lane >> 4;
    const int l16  = lane & 15;
    const int wr   = wave >> 2;       // row half (0/1): rows wr*128..+127
    const int wc   = wave & 3;        // col quarter (0..3): cols wc*64..+63

    // 3 staging buffers: 32 tiles (16 Q + 16 K) x 512 halves = 32KB each
    __shared__ _Float16 Sbuf[3][32 * 512];
    __shared__ float lred[4][256], nred[4][256];

    const int qbase = i * 32 + st2 * 16;      // Q row-block index (16 blocks)
    const int kbase = j * 32 + tb * 16;       // K row-block index (16 blocks)

    // per-wave staging sources (wave w stages rowblocks w and 8+w of each operand)
    const _Float16* gA0 = Qt + (size_t)(qbase + wave)     * (NKB * 512) + (size_t)lane * 8;
    const _Float16* gA1 = Qt + (size_t)(qbase + 8 + wave) * (NKB * 512) + (size_t)lane * 8;
    const _Float16* gB0 = Kt + (size_t)(kbase + wave)     * (NKB * 512) + (size_t)lane * 8;
    const _Float16* gB1 = Kt + (size_t)(kbase + 8 + wave) * (NKB * 512) + (size_t)lane * 8;

    floatx4 acc[8][4];
#pragma unroll
    for (int rt = 0; rt < 8; ++rt)
#pragma unroll
        for (int ct = 0; ct < 4; ++ct)
            acc[rt][ct] = (floatx4){0.f, 0.f, 0.f, 0.f};

    // prologue: stage K-tile 0 -> buf0, K-tile 1 -> buf1 (4 loads/wave each)
#pragma unroll
    for (int t = 0; t < 2; ++t) {
        _Float16* Lb = &Sbuf[t][0];
        async_tile16(gA0 + t * 512, Lb + (wave)      * 512);
        async_tile16(gA1 + t * 512, Lb + (8 + wave)  * 512);
        async_tile16(gB0 + t * 512, Lb + (16 + wave) * 512);
        async_tile16(gB1 + t * 512, Lb + (24 + wave) * 512);
    }
    // tile0's 4 loads retired (per wave), tile1's 4 stay in flight
    asm volatile("s_waitcnt vmcnt(4)\n\ts_barrier" ::: "memory");
    __builtin_amdgcn_sched_barrier(0);

    for (int t = 0; t < NKB; ++t) {
        const _Float16* Rb = &Sbuf[t % 3][0];
        _Float16*       Wb = &Sbuf[(t + 2) % 3][0];

        // ---------------- phase 0: bf (all cols) + af row-quad 0, MFMA rt 0..3 -------
        half8 bf[4], af[4];
#pragma unroll
        for (int ct = 0; ct < 4; ++ct)
            bf[ct] = *(const half8*)(Rb + (16 + wc * 4 + ct) * 512 + lane * 8);
#pragma unroll
        for (int rq = 0; rq < 4; ++rq)
            af[rq] = *(const half8*)(Rb + (wr * 8 + rq) * 512 + lane * 8);

        if (t + 2 < NKB) {   // stage A rows of K-tile t+2
            async_tile16(gA0 + (size_t)(t + 2) * 512, Wb + (wave)     * 512);
            async_tile16(gA1 + (size_t)(t + 2) * 512, Wb + (8 + wave) * 512);
        }
        __builtin_amdgcn_sched_barrier(0);
        asm volatile("s_barrier" ::: "memory");
        __builtin_amdgcn_sched_barrier(0);
        asm volatile("s_waitcnt lgkmcnt(0)" ::: "memory");
        __builtin_amdgcn_sched_barrier(0);

        __builtin_amdgcn_s_setprio(1);
#pragma unroll
        for (int rq = 0; rq < 4; ++rq)
#pragma unroll
            for (int ct = 0; ct < 4; ++ct)
                acc[rq][ct] = __builtin_amdgcn_mfma_f32_16x16x32_f16(af[rq], bf[ct], acc[rq][ct], 0, 0, 0);
        __builtin_amdgcn_s_setprio(0);
        __builtin_amdgcn_sched_barrier(0);
        asm volatile("s_barrier" ::: "memory");
        __builtin_amdgcn_sched_barrier(0);

        // ---------------- phase 1: af row-quad 1, MFMA rt 4..7 -----------------------
#pragma unroll
        for (int rq = 0; rq < 4; ++rq)
            af[rq] = *(const half8*)(Rb + (wr * 8 + 4 + rq) * 512 + lane * 8);

        if (t + 2 < NKB) {   // stage B rows of K-tile t+2
            async_tile16(gB0 + (size_t)(t + 2) * 512, Wb + (16 + wave) * 512);
            async_tile16(gB1 + (size_t)(t + 2) * 512, Wb + (24 + wave) * 512);
        }
        // K-tile boundary wait: retire tile t+1's loads (needed next iter), keep
        // tile t+2's 4 in flight. Tail (nothing issued this iter): drain.
        if (t + 2 < NKB) asm volatile("s_waitcnt vmcnt(4)" ::: "memory");
        else             asm volatile("s_waitcnt vmcnt(0)" ::: "memory");
        __builtin_amdgcn_sched_barrier(0);
        asm volatile("s_barrier" ::: "memory");
        __builtin_amdgcn_sched_barrier(0);
        asm volatile("s_waitcnt lgkmcnt(0)" ::: "memory");
        __builtin_amdgcn_sched_barrier(0);

        __builtin_amdgcn_s_setprio(1);
#pragma unroll
        for (int rq = 0; rq < 4; ++rq)
#pragma unroll
            for (int ct = 0; ct < 4; ++ct)
                acc[4 + rq][ct] = __builtin_amdgcn_mfma_f32_16x16x32_f16(af[rq], bf[ct], acc[4 + rq][ct], 0, 0, 0);
        __builtin_amdgcn_s_setprio(0);
        __builtin_amdgcn_sched_barrier(0);
        asm volatile("s_barrier" ::: "memory");
        __builtin_amdgcn_sched_barrier(0);
    }

    // ---- epilogue: sum-softmax partials (logits in [-1,1] -> no max needed) ----
    const float araw  = *alpha_p;
    const float alpha = araw >= 0.f ? araw : 0.01f * araw;   // leaky_relu

    const int* km = kmask + j * SEQ_ + tb * 256;
    int kmv[4]; float tgf[4];
#pragma unroll
    for (int ct = 0; ct < 4; ++ct) {
        int t_loc = wc * 64 + ct * 16 + l16;
        kmv[ct] = km[t_loc];
        tgf[ct] = (float)(tb * 256 + t_loc);
    }
#pragma unroll
    for (int rt = 0; rt < 8; ++rt) {
#pragma unroll
        for (int r = 0; r < 4; ++r) {
            float sgf = (float)(st2 * 256 + wr * 128 + rt * 16 + quad * 4 + r);
            float ps = 0.f, ns = 0.f;
#pragma unroll
            for (int ct = 0; ct < 4; ++ct) {
                float cv = acc[rt][ct][r];
                float e  = kmv[ct] ? __expf(cv * __expf(-alpha * fabsf(sgf - tgf[ct]))) : 0.f;
                ps += e;
                ns += e * cv;
            }
#pragma unroll
            for (int msk = 1; msk < 16; msk <<= 1) {
                ps += __shfl_xor(ps, msk, 64);
                ns += __shfl_xor(ns, msk, 64);
            }
            if (l16 == 0) {
                int rloc = wr * 128 + rt * 16 + quad * 4 + r;
                lred[wc][rloc] = ps;
                nred[wc][rloc] = ns;
            }
        }
    }
    __syncthreads();

    // merge 4 col-quarters; one (l,n) per row per t-half
    if (tid < 256) {
        float l = lred[0][tid] + lred[1][tid] + lred[2][tid] + lred[3][tid];
        float n = nred[0][tid] + nred[1][tid] + nred[2][tid] + nred[3][tid];
        size_t base = (((size_t)(i * KB_ + j) * SEQ_) + st2 * 256 + tid) * 4 + tb * 2;
        Pbuf[base]     = l;
        Pbuf[base + 1] = n;
    }
}

// ---------------- phase 2: merge t-halves, apply q_mask, reduce over s ----------------
__global__ __launch_bounds__(256)
void li_reduce(const float* __restrict__ Pbuf, const int* __restrict__ qmask,
               float* __restrict__ out)
{
    const int ij = blockIdx.x;
    const int i  = ij >> 4;           // KB_ == 16
    const int tid = threadIdx.x;
    __shared__ float red[4];

    float sum = 0.f;
#pragma unroll
    for (int rep = 0; rep < 2; ++rep) {
        int s = tid + rep * 256;
        float4 a = *(const float4*)(Pbuf + ((size_t)ij * SEQ_ + s) * 4);
        float l = a.x + a.z;
        float n = a.y + a.w;
        float sc = (l > 0.f) ? n / l : 0.f;
        if (qmask[i * SEQ_ + s] == 0) sc = 0.f;
        sum += sc;
    }
#pragma unroll
    for (int m = 1; m < 64; m <<= 1) sum += __shfl_xor(sum, m, 64);
    if ((tid & 63) == 0) red[tid >> 6] = sum;
    __syncthreads();
    if (tid == 0) out[ij] = red[0] + red[1] + red[2] + red[3];
}

extern "C" void kernel_launch(void* const* d_in, const int* in_sizes, int n_in,
                              void* d_out, int out_size, void* d_ws, size_t ws_size,
                              hipStream_t stream)
{
    const float* Q       = (const float*)d_in[0];
    const float* K       = (const float*)d_in[1];
    const float* alpha_p = (const float*)d_in[2];
    const int*   qmask   = (const int*)d_in[3];
    const int*   kmask   = (const int*)d_in[4];
    float*       out     = (float*)d_out;

    char* ws = (char*)d_ws;
    _Float16* Qt   = (_Float16*)ws;
    _Float16* Kt   = (_Float16*)(ws + (size_t)B_ * SEQ_ * HID_ * 2);
    float*    Pbuf = (float*)   (ws + (size_t)(B_ + KB_) * SEQ_ * HID_ * 2);

    prep_tile<<<QRB + KRB, 256, 0, stream>>>(Q, K, Qt, Kt);

    dim3 grid(4, KB_, B_);   // (st2*2+tb, j, i)
    li_part<<<grid, 512, 0, stream>>>(Qt, Kt, alpha_p, kmask, Pbuf);

    li_reduce<<<B_ * KB_, 256, 0, stream>>>(Pbuf, qmask, out);
}

// Round 3
// 146.565 us; speedup vs baseline: 1.0542x; 1.0542x over previous
//
#include <hip/hip_runtime.h>
#include <stdint.h>

#define B_   8
#define KB_  16
#define SEQ_ 512
#define HID_ 768

#define NKB  (HID_ / 32)         // 24 k-blocks (32 halves each) per row
#define QRB  (B_  * SEQ_ / 16)   // 256 Q row-blocks of 16 rows
#define KRB  (KB_ * SEQ_ / 16)   // 512 K row-blocks

typedef __attribute__((ext_vector_type(4))) _Float16 half4;
typedef __attribute__((ext_vector_type(8))) _Float16 half8;
typedef __attribute__((ext_vector_type(4))) float    floatx4;

#define GLOBAL_AS __attribute__((address_space(1)))
#define LDS_AS    __attribute__((address_space(3)))

// async 16B/lane global->LDS copy: LDS dest = base + lane*16 (wave-uniform base)
static __device__ __forceinline__ void async_tile16(const _Float16* g, _Float16* l)
{
    __builtin_amdgcn_global_load_lds((const GLOBAL_AS uint32_t*)g,
                                     (LDS_AS uint32_t*)l, 16, 0, 0);
}

// ---------------- prepass: L2-normalize rows -> fp16 in MFMA-fragment-tiled layout ----
// Tile = 16 rows x 32 k = 1KB, lane-major: element(row,k) at lane = row | ((k>>3)<<4),
// idx = k&7. One 256-thread block per 16-row block.
#define LP 776   // LDS row stride in halves

__global__ __launch_bounds__(256)
void prep_tile(const float* __restrict__ Q, const float* __restrict__ K,
               _Float16* __restrict__ Qt, _Float16* __restrict__ Kt)
{
    const int rb = blockIdx.x;   // 0..767
    const float* src;
    _Float16*    dst;
    if (rb < QRB) { src = Q + (size_t)rb * 16 * HID_;          dst = Qt + (size_t)rb * NKB * 512; }
    else          { src = K + (size_t)(rb - QRB) * 16 * HID_;  dst = Kt + (size_t)(rb - QRB) * NKB * 512; }

    __shared__ _Float16 Ls[16 * LP];
    const int wave = threadIdx.x >> 6;
    const int lane = threadIdx.x & 63;

#pragma unroll
    for (int rr = 0; rr < 4; ++rr) {
        int row = wave * 4 + rr;
        const float* s = src + (size_t)row * HID_;
        float4 v[3];
        float ss = 0.f;
#pragma unroll
        for (int it = 0; it < 3; ++it) {
            v[it] = *(const float4*)(s + lane * 4 + it * 256);
            ss += v[it].x * v[it].x + v[it].y * v[it].y + v[it].z * v[it].z + v[it].w * v[it].w;
        }
#pragma unroll
        for (int m = 1; m < 64; m <<= 1) ss += __shfl_xor(ss, m, 64);
        float sc = 1.0f / fmaxf(sqrtf(ss), 1e-12f);
#pragma unroll
        for (int it = 0; it < 3; ++it) {
            half4 h = { (_Float16)(v[it].x * sc), (_Float16)(v[it].y * sc),
                        (_Float16)(v[it].z * sc), (_Float16)(v[it].w * sc) };
            *(half4*)(Ls + row * LP + lane * 4 + it * 256) = h;
        }
    }
    __syncthreads();

#pragma unroll
    for (int rep = 0; rep < 6; ++rep) {
        int slot = rep * 256 + threadIdx.x;      // 0..1535 = 24 tiles x 64 lanes
        int kb   = slot >> 6;
        int ln   = slot & 63;
        int row  = ln & 15;
        int ko   = kb * 32 + (ln >> 4) * 8;
        half8 h = *(const half8*)(Ls + row * LP + ko);
        *(half8*)(dst + (size_t)kb * 512 + (size_t)ln * 8) = h;
    }
}

// ---------------- phase 1: GEMM (128x256 tile) + sum-softmax partials -----------------
// grid: x = st*2 + tb (8), y = j (16), z = i (8); 512 threads = 8 waves of 64x64.
// A (Q) is DMA-staged to double-buffered LDS (8 KB/buf); B (K) fragments are read
// DIRECTLY global->VGPR (L2-resident, 16B/lane coalesced) so only 1/3 of the former
// staged bytes sit on the per-step barrier-drain critical path.
__global__ __launch_bounds__(512, 4)
void li_part(const _Float16* __restrict__ Qt, const _Float16* __restrict__ Kt,
             const float* __restrict__ alpha_p, const int* __restrict__ kmask,
             float* __restrict__ Pbuf)
{
    const int st = blockIdx.x >> 1;   // s tile (0..3), 128 rows
    const int tb = blockIdx.x & 1;    // t half (0..1), 256 cols
    const int j  = blockIdx.y;
    const int i  = blockIdx.z;

    const int tid  = threadIdx.x;
    const int lane = tid & 63;
    const int wave = tid >> 6;        // 0..7
    const int quad = lane >> 4;
    const int l16  = lane & 15;
    const int wr   = wave >> 2;       // row half (0/1): rows wr*64..+63
    const int wc   = wave & 3;        // col quarter (0..3): cols wc*64..+63

    // A-only double-buffered staging: 8 tiles x 512 halves = 8KB per buffer
    __shared__ _Float16 As[2][8 * 512];
    __shared__ float lred[4][128], nred[4][128];

    const float araw  = *alpha_p;
    const float alpha = araw >= 0.f ? araw : 0.01f * araw;   // leaky_relu

    const int qbase = i * 32 + st * 8;        // Q row-block index (8 blocks)
    const int kbase = j * 32 + tb * 16;       // K row-block index (16 blocks)

    // wave w stages Q rowblock (qbase + w)
    const _Float16* gA = Qt + (size_t)(qbase + wave) * (NKB * 512) + (size_t)lane * 8;
    // direct-global B fragment pointers for this wave's 4 col-tiles
    const _Float16* gB[4];
#pragma unroll
    for (int ct = 0; ct < 4; ++ct)
        gB[ct] = Kt + (size_t)(kbase + wc * 4 + ct) * (NKB * 512) + (size_t)lane * 8;

    floatx4 acc[4][4];
#pragma unroll
    for (int rt = 0; rt < 4; ++rt)
#pragma unroll
        for (int ct = 0; ct < 4; ++ct)
            acc[rt][ct] = (floatx4){0.f, 0.f, 0.f, 0.f};

    // stage kb=0 A-tile into buffer 0 (1 DMA per wave)
    async_tile16(gA, &As[0][wave * 512]);

    for (int kb = 0; kb < NKB; ++kb) {
        const int b = kb & 1;
        __syncthreads();   // drains own staging (vmcnt) + fences prior reads of buf b^1
        if (kb + 1 < NKB)
            async_tile16(gA + (size_t)(kb + 1) * 512, &As[b ^ 1][wave * 512]);

        // B fragments straight from global (issue early; compiler inserts counted vmcnt)
        half8 bf[4];
#pragma unroll
        for (int ct = 0; ct < 4; ++ct)
            bf[ct] = *(const half8*)(gB[ct] + (size_t)kb * 512);

        const _Float16* Qs = &As[b][0];
        half8 af[4];
#pragma unroll
        for (int rt = 0; rt < 4; ++rt)
            af[rt] = *(const half8*)(Qs + (wr * 4 + rt) * 512 + lane * 8);

#pragma unroll
        for (int rt = 0; rt < 4; ++rt)
#pragma unroll
            for (int ct = 0; ct < 4; ++ct)
                acc[rt][ct] = __builtin_amdgcn_mfma_f32_16x16x32_f16(af[rt], bf[ct], acc[rt][ct], 0, 0, 0);
    }

    // ---- epilogue: sum-softmax partials (logits in [-1,1] -> no max needed) ----
    const int* km = kmask + j * SEQ_ + tb * 256;
    int kmv[4]; float tgf[4];
#pragma unroll
    for (int ct = 0; ct < 4; ++ct) {
        int t_loc = wc * 64 + ct * 16 + l16;
        kmv[ct] = km[t_loc];
        tgf[ct] = (float)(tb * 256 + t_loc);
    }
#pragma unroll
    for (int rt = 0; rt < 4; ++rt) {
#pragma unroll
        for (int r = 0; r < 4; ++r) {
            float sgf = (float)(st * 128 + wr * 64 + rt * 16 + quad * 4 + r);
            float ps = 0.f, ns = 0.f;
#pragma unroll
            for (int ct = 0; ct < 4; ++ct) {
                float cv = acc[rt][ct][r];
                float e  = kmv[ct] ? __expf(cv * __expf(-alpha * fabsf(sgf - tgf[ct]))) : 0.f;
                ps += e;
                ns += e * cv;
            }
#pragma unroll
            for (int msk = 1; msk < 16; msk <<= 1) {
                ps += __shfl_xor(ps, msk, 64);
                ns += __shfl_xor(ns, msk, 64);
            }
            if (l16 == 0) {
                int rloc = wr * 64 + rt * 16 + quad * 4 + r;
                lred[wc][rloc] = ps;
                nred[wc][rloc] = ns;
            }
        }
    }
    __syncthreads();

    // merge 4 col-quarters; one (l,n) per row per t-half
    if (tid < 128) {
        float l = lred[0][tid] + lred[1][tid] + lred[2][tid] + lred[3][tid];
        float n = nred[0][tid] + nred[1][tid] + nred[2][tid] + nred[3][tid];
        size_t base = (((size_t)(i * KB_ + j) * SEQ_) + st * 128 + tid) * 4 + tb * 2;
        Pbuf[base]     = l;
        Pbuf[base + 1] = n;
    }
}

// ---------------- phase 2: merge t-halves, apply q_mask, reduce over s ----------------
__global__ __launch_bounds__(256)
void li_reduce(const float* __restrict__ Pbuf, const int* __restrict__ qmask,
               float* __restrict__ out)
{
    const int ij = blockIdx.x;
    const int i  = ij >> 4;           // KB_ == 16
    const int tid = threadIdx.x;
    __shared__ float red[4];

    float sum = 0.f;
#pragma unroll
    for (int rep = 0; rep < 2; ++rep) {
        int s = tid + rep * 256;
        float4 a = *(const float4*)(Pbuf + ((size_t)ij * SEQ_ + s) * 4);
        float l = a.x + a.z;
        float n = a.y + a.w;
        float sc = (l > 0.f) ? n / l : 0.f;
        if (qmask[i * SEQ_ + s] == 0) sc = 0.f;
        sum += sc;
    }
#pragma unroll
    for (int m = 1; m < 64; m <<= 1) sum += __shfl_xor(sum, m, 64);
    if ((tid & 63) == 0) red[tid >> 6] = sum;
    __syncthreads();
    if (tid == 0) out[ij] = red[0] + red[1] + red[2] + red[3];
}

extern "C" void kernel_launch(void* const* d_in, const int* in_sizes, int n_in,
                              void* d_out, int out_size, void* d_ws, size_t ws_size,
                              hipStream_t stream)
{
    const float* Q       = (const float*)d_in[0];
    const float* K       = (const float*)d_in[1];
    const float* alpha_p = (const float*)d_in[2];
    const int*   qmask   = (const int*)d_in[3];
    const int*   kmask   = (const int*)d_in[4];
    float*       out     = (float*)d_out;

    char* ws = (char*)d_ws;
    _Float16* Qt   = (_Float16*)ws;
    _Float16* Kt   = (_Float16*)(ws + (size_t)B_ * SEQ_ * HID_ * 2);
    float*    Pbuf = (float*)   (ws + (size_t)(B_ + KB_) * SEQ_ * HID_ * 2);

    prep_tile<<<QRB + KRB, 256, 0, stream>>>(Q, K, Qt, Kt);

    dim3 grid(8, KB_, B_);   // (st*2+tb, j, i)
    li_part<<<grid, 512, 0, stream>>>(Qt, Kt, alpha_p, kmask, Pbuf);

    li_reduce<<<B_ * KB_, 256, 0, stream>>>(Pbuf, qmask, out);
}